// Round 8
// baseline (565.248 us; speedup 1.0000x reference)
//
#include <hip/hip_runtime.h>
#include <cstdint>
#include <cstddef>

typedef short short8 __attribute__((ext_vector_type(8)));
typedef short s16x4 __attribute__((ext_vector_type(4)));
typedef float f32x4 __attribute__((ext_vector_type(4)));

typedef const __attribute__((address_space(1))) void* gas_ptr;
typedef __attribute__((address_space(3))) void* las_ptr;

__device__ __forceinline__ unsigned short f2bf(float f) {
    unsigned int u = __float_as_uint(f);
    u += 0x7fffu + ((u >> 16) & 1u);          // RNE (finite inputs)
    return (unsigned short)(u >> 16);
}
__device__ __forceinline__ float bf2f(unsigned short s) {
    return __uint_as_float(((unsigned int)s) << 16);
}
__device__ __forceinline__ float sigmoid_f(float z) {
    return __builtin_amdgcn_rcpf(1.0f + __expf(-z));
}
__device__ __forceinline__ void async_copy16(const void* gp, void* lp) {
    __builtin_amdgcn_global_load_lds((gas_ptr)gp, (las_ptr)lp, 16, 0, 0);
}

// ---------------- converters ----------------
// x: [32768,1024] f32 -> bf16, same layout. 8 elems/thread.
__global__ __launch_bounds__(256) void cvt_x_kernel(const float* __restrict__ in,
                                                    unsigned short* __restrict__ out) {
    size_t i = ((size_t)blockIdx.x * 256 + threadIdx.x) * 8;
    float4 v0 = *(const float4*)(in + i);
    float4 v1 = *(const float4*)(in + i + 4);
    short8 o;
    o[0]=(short)f2bf(v0.x); o[1]=(short)f2bf(v0.y); o[2]=(short)f2bf(v0.z); o[3]=(short)f2bf(v0.w);
    o[4]=(short)f2bf(v1.x); o[5]=(short)f2bf(v1.y); o[6]=(short)f2bf(v1.z); o[7]=(short)f2bf(v1.w);
    *(short8*)(out + i) = o;
}

// W: [1024,4096] f32 -> W_T bf16 [4096,1024]. 64x64 LDS tiles.
__global__ __launch_bounds__(256) void cvt_w_kernel(const float* __restrict__ W,
                                                    unsigned short* __restrict__ Wt) {
    __shared__ unsigned short tile[64][65];
    int bk = blockIdx.x >> 6, bn = blockIdx.x & 63;
    int k0 = bk * 64, n0 = bn * 64;
    int t = threadIdx.x;
    int cr = t >> 6;          // 0..3
    int cc = t & 63;          // 0..63
#pragma unroll
    for (int i = 0; i < 16; ++i) {
        int row = i * 4 + cr;
        tile[row][cc] = f2bf(W[(size_t)(k0 + row) * 4096 + n0 + cc]);
    }
    __syncthreads();
#pragma unroll
    for (int i = 0; i < 16; ++i) {
        int nrow = i * 4 + cr;
        Wt[(size_t)(n0 + nrow) * 1024 + k0 + cc] = tile[cc][nrow];
    }
}

// ---------------- GEMM ----------------
// (unchanged — 255 us, MfmaUtil 52%)
// Output: gT bf16 TIME-MAJOR blocked [T/8][b][gate][u][8].
__global__ __launch_bounds__(256, 2) void gemm_kernel(const unsigned short* __restrict__ A,
                                                      const unsigned short* __restrict__ Bt,
                                                      const float* __restrict__ bias,
                                                      unsigned short* __restrict__ gT) {
    __shared__ __align__(16) unsigned short As[128 * 64];
    __shared__ __align__(16) unsigned short Bs[128 * 64];

    // band swizzle: 8 m-tiles x 32 n-tiles per band, n fastest
    int bid = blockIdx.x;
    int band = bid >> 8;
    int r = bid & 255;
    int mt = band * 8 + (r >> 5);
    int nt = r & 31;
    int m0 = mt * 128, n0 = nt * 128;

    int tidx = threadIdx.x;
    int lane = tidx & 63, wv = tidx >> 6;
    int wm = wv >> 1, wn = wv & 1;
    int l15 = lane & 15, quad = lane >> 4;

    f32x4 acc[4][4] = {};

    for (int k0 = 0; k0 < 1024; k0 += 64) {
        __syncthreads();
#pragma unroll
        for (int i = 0; i < 4; ++i) {
            int ci = (wv * 4 + i) * 64 + lane;      // 0..1023
            int row = ci >> 3, cc = ci & 7;
            int sc = (cc ^ (row & 7)) << 3;         // swizzled k-offset (elements)
            const unsigned short* ga = A + (size_t)(m0 + row) * 1024 + k0 + sc;
            async_copy16(ga, (char*)As + (wv * 4 + i) * 1024);
            const unsigned short* gb = Bt + (size_t)(n0 + row) * 1024 + k0 + sc;
            async_copy16(gb, (char*)Bs + (wv * 4 + i) * 1024);
        }
        __syncthreads();
#pragma unroll
        for (int kt = 0; kt < 2; ++kt) {
            short8 af[4], bf[4];
#pragma unroll
            for (int mt2 = 0; mt2 < 4; ++mt2) {
                int row = wm * 64 + mt2 * 16 + l15;
                int kc = kt * 4 + quad;
                af[mt2] = *(const short8*)((const char*)As + row * 128 + ((kc ^ (row & 7)) << 4));
            }
#pragma unroll
            for (int nt2 = 0; nt2 < 4; ++nt2) {
                int rown = wn * 64 + nt2 * 16 + l15;
                int kc = kt * 4 + quad;
                bf[nt2] = *(const short8*)((const char*)Bs + rown * 128 + ((kc ^ (rown & 7)) << 4));
            }
#pragma unroll
            for (int mt2 = 0; mt2 < 4; ++mt2)
#pragma unroll
                for (int nt2 = 0; nt2 < 4; ++nt2)
                    acc[mt2][nt2] = __builtin_amdgcn_mfma_f32_16x16x32_bf16(
                        af[mt2], bf[nt2], acc[mt2][nt2], 0, 0, 0);
        }
    }

    // epilogue: C/D layout col=lane&15, row=quad*4+reg.
#pragma unroll
    for (int mt2 = 0; mt2 < 4; ++mt2) {
        int mbase = m0 + wm * 64 + mt2 * 16 + quad * 4;
        int b_ = mbase >> 10, t_ = mbase & 1023;
#pragma unroll
        for (int nt2 = 0; nt2 < 4; ++nt2) {
            int n = n0 + wn * 64 + nt2 * 16 + l15;
            int gate = n >> 10, u = n & 1023;
            float bv = bias[n];
            s16x4 pk;
            pk[0] = (short)f2bf(acc[mt2][nt2][0] + bv);
            pk[1] = (short)f2bf(acc[mt2][nt2][1] + bv);
            pk[2] = (short)f2bf(acc[mt2][nt2][2] + bv);
            pk[3] = (short)f2bf(acc[mt2][nt2][3] + bv);
            // gT[t_>>3][b_][gate][u][t_&7]
            size_t off = ((((size_t)(t_ >> 3) * 32 + (size_t)b_) * 4 + (size_t)gate) << 13)
                         + ((size_t)u << 3) + (size_t)(t_ & 7);
            *(s16x4*)(gT + off) = pk;
        }
    }
}

// ---------------- fused scan: full role separation ----------------
// gT bf16 time-major [T/8][B][4][U][8]; h f32 [B,T,U].
// Block = 512 thr (8 waves). Roles:
//   wave 0    = chain: recurrence from sbuf, h -> LDS hbuf. NO global stores,
//               so its barrier waits are lgkmcnt(0) only (~30 cyc).
//   waves 1-4 = stagers: global_load_lds chunk k+1 -> sbuf[(k+1)&1]; own
//               vmcnt(0) pre-barrier (drain overlaps chain compute).
//   waves 5-7 = writers: hbuf[(k-1)&1] -> h. NEVER wait vmcnt: stores float
//               across barriers, drained only at kernel end.
// Raw s_barrier (NOT __syncthreads) so no wave is forced to vmcnt(0)-drain
// h-stores — the coupling present in every previous (null) scan variant.
// Chunk = 32 t. sbuf 2x16KB + hbuf 2x8KB = 48 KB -> 2+ blocks/CU.
__global__ __launch_bounds__(512, 4) void scan_kernel(const unsigned short* __restrict__ gT,
                                                      const float* __restrict__ c0,
                                                      const float* __restrict__ Vr,
                                                      const float* __restrict__ Vf,
                                                      float* __restrict__ h) {
    // sbuf: [buf 2][gate 4][tbi 4][u 64][t 8] bf16
    __shared__ __align__(16) unsigned short sbuf[2 * 4 * 4 * 512];
    // hbuf: [buf 2][t_local 32][u 64] f32
    __shared__ __align__(16) float hbuf[2][32][64];

    const int NCH = 32;                       // 32 chunks x 32 t = 1024 t
    int blk = blockIdx.x;                     // 0..511
    int b = blk >> 4;
    int u0 = (blk & 15) << 6;
    int tid = threadIdx.x;
    int wv = tid >> 6;
    int lane = tid & 63;

    // gT element offset: tb<<20 + b*32768 + gate*8192 + u*8
    size_t gbase = (size_t)b * 32768 + ((size_t)(u0 + lane) << 3);

    if (wv >= 1 && wv <= 4) {
        // prologue: chunk 0 -> buf 0. 16 planes (4 gates x 4 tbi) / 4 waves.
        for (int p = wv - 1; p < 16; p += 4) {
            int gate = p >> 2, tbi = p & 3;
            const unsigned short* src = gT + ((size_t)tbi << 20) + gbase + gate * 8192;
            char* dst = (char*)sbuf + gate * 4096 + tbi * 1024 + lane * 16;
            async_copy16(src, dst);
        }
        asm volatile("s_waitcnt vmcnt(0)" ::: "memory");
    }
    __builtin_amdgcn_s_barrier();

    float c = 0.0f, vf = 0.0f, vr = 0.0f;
    if (wv == 0) {
        int u = u0 + lane;
        c = c0[(b << 10) + u];
        vf = Vf[u];
        vr = Vr[u];
    }
    float* hb = h + ((size_t)b << 20) + u0 + lane;

    for (int k = 0; k < NCH; ++k) {
        if (wv == 0) {
            // ---- chain: chunk k from sbuf[k&1] into hbuf[k&1] ----
            const unsigned short* ls = sbuf + (k & 1) * 8192 + (size_t)lane * 8;
#pragma unroll
            for (int tbi = 0; tbi < 4; ++tbi) {
                short8 a1 = *(const short8*)(ls + tbi * 512);
                short8 a2 = *(const short8*)(ls + 2048 + tbi * 512);
                short8 a3 = *(const short8*)(ls + 4096 + tbi * 512);
                short8 a4 = *(const short8*)(ls + 6144 + tbi * 512);
#pragma unroll
                for (int i = 0; i < 8; ++i) {
                    float x1 = bf2f((unsigned short)a1[i]);
                    float x2 = bf2f((unsigned short)a2[i]);
                    float x3 = bf2f((unsigned short)a3[i]);
                    float x4 = bf2f((unsigned short)a4[i]);
                    float f  = sigmoid_f(x1 + vf * c);
                    float cp = c;
                    c = fmaf(f, c - x2, x2);            // c_t (exact op sequence)
                    float rr = sigmoid_f(x3 + vr * cp); // uses c_{t-1}
                    float hv = fmaf(rr, c - x4, x4);
                    hbuf[k & 1][tbi * 8 + i][lane] = hv;
                }
            }
            asm volatile("s_waitcnt lgkmcnt(0)" ::: "memory");  // hbuf visible
        } else if (wv <= 4) {
            // ---- stagers: chunk k+1 -> sbuf[(k+1)&1] ----
            if (k + 1 < NCH) {
                int nb = (k + 1) & 1;
                for (int p = wv - 1; p < 16; p += 4) {
                    int gate = p >> 2, tbi = p & 3;
                    const unsigned short* src =
                        gT + ((size_t)((k + 1) * 4 + tbi) << 20) + gbase + gate * 8192;
                    char* dst = (char*)sbuf + nb * 16384 + gate * 4096 + tbi * 1024 + lane * 16;
                    async_copy16(src, dst);
                }
            }
            asm volatile("s_waitcnt vmcnt(0)" ::: "memory");
        } else {
            // ---- writers: chunk k-1 from hbuf[(k-1)&1] -> h (no vmcnt wait) ----
            if (k > 0) {
                int cb = (k - 1) & 1;
                int tg0 = (k - 1) * 32;
                for (int t = wv - 5; t < 32; t += 3) {
                    float v = hbuf[cb][t][lane];
                    hb[(size_t)(tg0 + t) << 10] = v;
                }
            }
        }
        __builtin_amdgcn_s_barrier();
    }

    // epilogue: writers store chunk NCH-1
    if (wv >= 5) {
        int cb = (NCH - 1) & 1;
        int tg0 = (NCH - 1) * 32;
        for (int t = wv - 5; t < 32; t += 3) {
            float v = hbuf[cb][t][lane];
            hb[(size_t)(tg0 + t) << 10] = v;
        }
    }
}

extern "C" void kernel_launch(void* const* d_in, const int* in_sizes, int n_in,
                              void* d_out, int out_size, void* d_ws, size_t ws_size,
                              hipStream_t stream) {
    const float* x  = (const float*)d_in[0];
    // d_in[1] = h0 (unused by reference)
    const float* c0 = (const float*)d_in[2];
    const float* W  = (const float*)d_in[3];
    const float* b  = (const float*)d_in[4];
    const float* Vr = (const float*)d_in[5];
    const float* Vf = (const float*)d_in[6];
    float* h = (float*)d_out;

    char* ws = (char*)d_ws;
    unsigned short* xb = (unsigned short*)ws;                         // 64 MB
    unsigned short* wt = (unsigned short*)(ws + (size_t)67108864);    // 8 MB
    unsigned short* gT = (unsigned short*)(ws + (size_t)75497472);    // 256 MB

    cvt_x_kernel<<<16384, 256, 0, stream>>>(x, xb);
    cvt_w_kernel<<<1024, 256, 0, stream>>>(W, wt);
    gemm_kernel<<<8192, 256, 0, stream>>>(xb, wt, b, gT);
    scan_kernel<<<512, 512, 0, stream>>>(gT, c0, Vr, Vf, h);
}